// Round 20
// baseline (233.885 us; speedup 1.0000x reference)
//
#include <hip/hip_runtime.h>

// Problem constants
#define NN   65536      // N nodes
#define NE   524288     // E edges
#define EPG  8192       // edges per graph

// Output float offsets in d_out (total 10111552 floats)
#define O1 7913472      // ei_new (2*E)
#define O2 8962048      // ea_new (E)
#define O3 9486336      // batch_out (30912)
#define O4 9517248      // perm (30912)
#define O5 9548160      // score_perm (30912)
#define O6 9579072      // sentence_scores (4096)
#define O7 9583168      // sentence_batch (4096)
#define O8 9587264      // keep (E)

// Scratch placement (float offsets), lifetime-verified (same as R9-R19):
#define CSR_OFF    8388608
#define DINV_OFF   9437184
#define Z_OFF      9502720
#define W1HI_OFF   9568256
#define RSTART_OFF 9633792
#define CURSOR_OFF 9699344
#define W1LO_OFF   9764880
#define HIST_OFF   9830416
#define YLO_OFF    4194304   // ushort-plane offsets: yhi at float 0, ylo at float 4194304

typedef __attribute__((ext_vector_type(8))) short bfrag;
typedef __attribute__((ext_vector_type(16))) float f32x16;
typedef __attribute__((ext_vector_type(8))) unsigned short us8;
typedef __attribute__((ext_vector_type(2))) unsigned long long u64x2;

__device__ __forceinline__ unsigned monof(float f) {
  unsigned u = __float_as_uint(f);
  return (u & 0x80000000u) ? ~u : (u | 0x80000000u);  // ascending monotone map
}

__device__ __forceinline__ unsigned short bf16rne(float f) {
  unsigned u = __float_as_uint(f);
  return (unsigned short)((u + 0x7FFFu + ((u >> 16) & 1u)) >> 16);
}

// Merged: zero hist/z (blocks 0..255) + W1 split/transpose (blocks 256..287)
__global__ __launch_bounds__(256) void k_zero_w1t(unsigned long long* __restrict__ hist,
    float* __restrict__ z, const float* __restrict__ W1,
    unsigned short* __restrict__ hi, unsigned short* __restrict__ lo) {
  __shared__ unsigned short sh[64][72], sl[64][72];
  int b = blockIdx.x, t = threadIdx.x;
  if (b < 256) {
    int n = b * 256 + t;
    hist[n] = 0ull;
    z[n] = 0.0f;
    return;
  }
  int bb = b - 256;
  int bk = bb & 3, bc = bb >> 2;
  int k0 = bk * 64, c0 = bc * 64;
#pragma unroll
  for (int s = 0; s < 16; ++s) {
    int i = t + s * 256;
    int k = i >> 6, c = i & 63;
    float v = W1[(k0 + k) * 512 + c0 + c];
    unsigned short h = bf16rne(v);
    float hf = __uint_as_float((unsigned)h << 16);
    sh[c][k] = h;
    sl[c][k] = bf16rne(v - hf);
  }
  __syncthreads();
#pragma unroll
  for (int s = 0; s < 16; ++s) {
    int i = t + s * 256;
    int c = i >> 6, k = i & 63;
    hi[(c0 + c) * 256 + k0 + k] = sh[c][k];
    lo[(c0 + c) * 256 + k0 + k] = sl[c][k];
  }
}

// One packed u64 atomic per edge: count in bits>=40, wsum fixed-point 2^-20 below.
__global__ void k_hist(const int* __restrict__ ei, const float* __restrict__ w,
                       unsigned long long* __restrict__ hist) {
  int e = blockIdx.x * 256 + threadIdx.x;
  if (e < NE) {
    int c = ei[NE + e];
    unsigned long long add = (1ull << 40) |
        (unsigned long long)(unsigned)__float2uint_rn(w[e] * 1048576.0f);
    atomicAdd(&hist[c], add);
  }
}

// Per graph: exclusive prefix over 1024 bins -> rstart/cursor; dinv from fixed-point wsum.
__global__ __launch_bounds__(256) void k_prefix(const unsigned long long* __restrict__ hist,
    unsigned* __restrict__ rstart, unsigned* __restrict__ cursor, float* __restrict__ dinv) {
  __shared__ unsigned tmp[2][256];
  int g = blockIdx.x, t = threadIdx.x;
  int base = g << 10;
  unsigned c[4], sum = 0;
  unsigned long long hv[4];
#pragma unroll
  for (int u = 0; u < 4; ++u) {
    hv[u] = hist[base + t * 4 + u];
    c[u] = (unsigned)(hv[u] >> 40);
    sum += c[u];
  }
  tmp[0][t] = sum;
  __syncthreads();
  int pin = 0;
  for (int off = 1; off < 256; off <<= 1) {
    int pout = pin ^ 1;
    unsigned v = tmp[pin][t];
    if (t >= off) v += tmp[pin][t - off];
    tmp[pout][t] = v;
    __syncthreads();
    pin = pout;
  }
  unsigned run = (t == 0) ? 0u : tmp[pin][t - 1];
#pragma unroll
  for (int u = 0; u < 4; ++u) {
    unsigned pos = (unsigned)(g << 13) + run;   // g*8192 + prefix
    rstart[base + t * 4 + u] = pos;
    cursor[base + t * 4 + u] = pos;
    run += c[u];
  }
#pragma unroll
  for (int u = 0; u < 4; ++u) {
    int n = base + t * 4 + u;
    float wsum = 1.0f + (float)(hv[u] & ((1ull << 40) - 1)) * 9.5367431640625e-07f;
    dinv[n] = rsqrtf(wsum);
  }
  if (g == 0 && t == 0) rstart[NN] = NE;
}

// Scatter edges to dest-sorted CSR:
// entry = coef<<32 | src_local<<15 | src_local*17   (pre-scaled LDS row offset)
__global__ void k_scatter(const int* __restrict__ ei, const float* __restrict__ w,
                          const float* __restrict__ dinv, unsigned* __restrict__ cursor,
                          unsigned long long* __restrict__ csr) {
  int e = blockIdx.x * 256 + threadIdx.x;
  if (e < NE) {
    int r = ei[e], c = ei[NE + e];
    float cf = w[e] * dinv[r] * dinv[c];
    unsigned pos = atomicAdd(&cursor[c], 1u);
    unsigned sl = (unsigned)(r & 1023);
    csr[pos] = ((unsigned long long)__float_as_uint(cf) << 32) |
               (sl << 15) | (sl * 17u);
  }
}

// Aggregate x over normalized adjacency -> y bf16 hi/lo planes.
// (At structural floor: LDS-throughput bound, ~3 LDS ops/edge-visit-lane with
// unavoidable 4-way read aliasing. Whole-graph CSR in LDS, stride-17 xs,
// 8 lanes/edge, 2 cols/lane, sentinel-zero clamp, 1024 threads, 140 KB LDS.)
__global__ __launch_bounds__(1024, 1) void k_aggx(const float* __restrict__ x,
    const unsigned long long* __restrict__ csr, const unsigned* __restrict__ rstart,
    const float* __restrict__ dinv, unsigned short* __restrict__ yhi,
    unsigned short* __restrict__ ylo, int gbase) {
  __shared__ float xs[1024 * 17];          // 68 KB, stride-17 rows
  __shared__ unsigned long long es[8193];  // 64 KB CSR + zero sentinel
  __shared__ unsigned rp[1025];            // local segment starts
  __shared__ float dv2[1024];
  int bid = blockIdx.x;
  int g  = bid & 31;                // graph g -> XCD g%8 (L2 locality)
  int cc = bid >> 5;                // 16 chunks of 16 columns
  int gg = gbase + g;
  int c0 = cc * 16;
  int t = threadIdx.x;              // 0..1023
  int nbase = gg << 10;
  unsigned ebase = (unsigned)gg << 13;
  {
    rp[t] = rstart[nbase + t] - ebase;
    float dv = dinv[nbase + t];
    dv2[t] = dv * dv;
  }
  if (t == 0) { rp[1024] = 8192u; es[8192] = 0ull; }
  // stage whole-graph CSR: 4096 x 16B, 4 per thread
  {
    const u64x2* src = (const u64x2*)(csr + ebase);
    u64x2* dst = (u64x2*)es;
#pragma unroll
    for (int i = 0; i < 4; ++i)
      dst[t + i * 1024] = src[t + i * 1024];
  }
  // stage x[:, c0:c0+16]: float4 global loads, scalar LDS writes
#pragma unroll
  for (int s = 0; s < 4; ++s) {
    int i = t + s * 1024;           // float4-slot: row = i>>2, quad = i&3
    int row = i >> 2, q = (i & 3) * 4;
    float4 v = *(const float4*)&x[(nbase + row) * 256 + c0 + q];
    float* d = &xs[row * 17 + q];
    d[0] = v.x; d[1] = v.y; d[2] = v.z; d[3] = v.w;
  }
  __syncthreads();
  int jj = t & 7;                   // 2-col lane: cols c0+2jj, c0+2jj+1
  int h  = (t >> 3) & 1;            // half: segment d0 (h=0) or d1 (h=1)
  int grp = t >> 4;                 // 64 groups of 16 lanes
  int dbase = grp * 16;             // group owns dests [dbase, dbase+16)
  int j2 = 2 * jj;
  for (int dd = 0; dd < 8; ++dd) {
    int d0 = dbase + dd;
    unsigned pA = rp[d0], qA = rp[d0 + 1];
    unsigned pB = rp[d0 + 8], qB = rp[d0 + 9];
    int L0 = (int)(qA - pA), L1 = (int)(qB - pB);
    int L = L0 > L1 ? L0 : L1;      // group-uniform trip count
    int d = d0 + 8 * h;             // this half's dest
    unsigned p = h ? pB : pA;
    unsigned q = h ? qB : qA;
    int dofs = d * 17 + j2;
    float dv = dv2[d];
    float ax = dv * xs[dofs], ay = dv * xs[dofs + 1];
    for (int k = 0; k < L; k += 4) {
      unsigned long long cv[4];
#pragma unroll
      for (int u = 0; u < 4; ++u) {
        unsigned a = p + (unsigned)(k + u);
        cv[u] = es[a < q ? a : 8192u];   // sentinel: coef 0
      }
#pragma unroll
      for (int u = 0; u < 4; ++u) {
        float cf = __uint_as_float((unsigned)(cv[u] >> 32));
        unsigned o = ((unsigned)cv[u] & 0x7FFFu) + (unsigned)j2;
        ax += cf * xs[o];
        ay += cf * xs[o + 1];
      }
    }
    int idx = ((g << 10) + d) * 256 + c0 + j2;
    unsigned short hx = bf16rne(ax), hy = bf16rne(ay);
    float lx = ax - __uint_as_float((unsigned)hx << 16);
    float ly = ay - __uint_as_float((unsigned)hy << 16);
    *(unsigned*)&yhi[idx] = (unsigned)hx | ((unsigned)hy << 16);
    *(unsigned*)&ylo[idx] = (unsigned)bf16rne(lx) | ((unsigned)bf16rne(ly) << 16);
  }
}

// MFMA GEMM: 512 threads, 128x256 tile, double-buffered LDS (1 barrier/k-step),
// now using mfma_f32_32x32x16_bf16 (24 MFMA/wave/step instead of 48 16x16x32;
// 32x32 C/D layout per guide: col=lane&31, row=(reg&3)+8*(reg>>2)+4*(lane>>5)).
// bf16 hi/lo 3-product split, fused +b1 -> LeakyReLU -> dot W2 -> atomic z.
__global__ __launch_bounds__(512, 1) void k_gemm(
    const unsigned short* __restrict__ yhi, const unsigned short* __restrict__ ylo,
    const unsigned short* __restrict__ w1hi, const unsigned short* __restrict__ w1lo,
    const float* __restrict__ b1, const float* __restrict__ W2,
    float* __restrict__ z, int node_base) {
  __shared__ unsigned short Ah_s[2][128 * 40], Al_s[2][128 * 40];
  __shared__ unsigned short Bh_s[2][256 * 40], Bl_s[2][256 * 40];
  int bx = blockIdx.x & 1, by = blockIdx.x >> 1;
  int r0 = by * 128, c0 = bx * 256;
  int t = threadIdx.x;
  int lane = t & 63, wid = t >> 6;           // 8 waves
  int wr = wid >> 2, wc = wid & 3;           // wave tile origin (wr*64, wc*64)
  int lr = lane & 31, hg = lane >> 5;        // 32-lane row/col, k-half-group
  f32x16 acc[2][2];
#pragma unroll
  for (int m = 0; m < 2; ++m)
#pragma unroll
    for (int n = 0; n < 2; ++n)
      acc[m][n] = (f32x16){0.0f,0.0f,0.0f,0.0f,0.0f,0.0f,0.0f,0.0f,
                           0.0f,0.0f,0.0f,0.0f,0.0f,0.0f,0.0f,0.0f};
  // staging coords: A rows (1 us8/plane), B cols (2 us8/plane)
  int ar = t >> 2, ak = (t & 3) * 8;         // A: row 0..127, k-chunk
  int bc = t >> 1, bk = (t & 1) * 16;        // B: col 0..255, k-chunks bk, bk+8
  const unsigned short* pya = &yhi [(r0 + ar) * 256 + ak];
  const unsigned short* pyb = &ylo [(r0 + ar) * 256 + ak];
  const unsigned short* pw0 = &w1hi[(c0 + bc) * 256 + bk];
  const unsigned short* pw1 = &w1lo[(c0 + bc) * 256 + bk];
  us8 va, vb, vc0, vc1, vd0, vd1;
  // prologue: stage k-step 0 into buf 0
  va  = *(const us8*)&pya[0];
  vb  = *(const us8*)&pyb[0];
  vc0 = *(const us8*)&pw0[0];
  vc1 = *(const us8*)&pw0[8];
  vd0 = *(const us8*)&pw1[0];
  vd1 = *(const us8*)&pw1[8];
  *(us8*)&Ah_s[0][ar * 40 + ak] = va;
  *(us8*)&Al_s[0][ar * 40 + ak] = vb;
  *(us8*)&Bh_s[0][bc * 40 + bk] = vc0;
  *(us8*)&Bh_s[0][bc * 40 + bk + 8] = vc1;
  *(us8*)&Bl_s[0][bc * 40 + bk] = vd0;
  *(us8*)&Bl_s[0][bc * 40 + bk + 8] = vd1;
  __syncthreads();
#pragma unroll
  for (int s = 0; s < 8; ++s) {
    int cur = s & 1, nxt = cur ^ 1;
    int kn = (s < 7) ? (s + 1) * 32 : s * 32;  // clamped prefetch (branch-free)
    va  = *(const us8*)&pya[kn];
    vb  = *(const us8*)&pyb[kn];
    vc0 = *(const us8*)&pw0[kn];
    vc1 = *(const us8*)&pw0[kn + 8];
    vd0 = *(const us8*)&pw1[kn];
    vd1 = *(const us8*)&pw1[kn + 8];
    // fragments: A row = wr*64+m*32+lr, k = kh*16 + hg*8 (lane k-convention
    // matching the verified 16x16 pattern scaled to 32 rows / K=16)
    bfrag Ah[2][2], Al[2][2], Bh[2][2], Bl[2][2];
#pragma unroll
    for (int m = 0; m < 2; ++m)
#pragma unroll
      for (int kh = 0; kh < 2; ++kh) {
        int ra = (wr * 64 + m * 32 + lr) * 40 + kh * 16 + hg * 8;
        Ah[m][kh] = *(const bfrag*)&Ah_s[cur][ra];
        Al[m][kh] = *(const bfrag*)&Al_s[cur][ra];
        int rb = (wc * 64 + m * 32 + lr) * 40 + kh * 16 + hg * 8;
        Bh[m][kh] = *(const bfrag*)&Bh_s[cur][rb];
        Bl[m][kh] = *(const bfrag*)&Bl_s[cur][rb];
      }
#pragma unroll
    for (int m = 0; m < 2; ++m)
#pragma unroll
      for (int n = 0; n < 2; ++n)
#pragma unroll
        for (int kh = 0; kh < 2; ++kh) {
          acc[m][n] = __builtin_amdgcn_mfma_f32_32x32x16_bf16(Ah[m][kh], Bh[n][kh], acc[m][n], 0, 0, 0);
          acc[m][n] = __builtin_amdgcn_mfma_f32_32x32x16_bf16(Ah[m][kh], Bl[n][kh], acc[m][n], 0, 0, 0);
          acc[m][n] = __builtin_amdgcn_mfma_f32_32x32x16_bf16(Al[m][kh], Bh[n][kh], acc[m][n], 0, 0, 0);
        }
    // write next step's data to the alternate buffer, then the single barrier
    *(us8*)&Ah_s[nxt][ar * 40 + ak] = va;
    *(us8*)&Al_s[nxt][ar * 40 + ak] = vb;
    *(us8*)&Bh_s[nxt][bc * 40 + bk] = vc0;
    *(us8*)&Bh_s[nxt][bc * 40 + bk + 8] = vc1;
    *(us8*)&Bl_s[nxt][bc * 40 + bk] = vd0;
    *(us8*)&Bl_s[nxt][bc * 40 + bk + 8] = vd1;
    __syncthreads();
  }
  // epilogue: +b1, LeakyReLU, dot W2 over cols (n, lane&31), reduce over the
  // 32 col-lanes (width-32 butterfly), atomic into z. Two writer lanes/wave
  // (lr==0, hg=0/1) each own 16 rows per m: row=(i&3)+8*(i>>2)+4*hg.
  float p[2][16];
#pragma unroll
  for (int m = 0; m < 2; ++m)
#pragma unroll
    for (int i = 0; i < 16; ++i) p[m][i] = 0.0f;
#pragma unroll
  for (int n = 0; n < 2; ++n) {
    int col = c0 + wc * 64 + n * 32 + lr;
    float b1v = b1[col], w2v = W2[col];
#pragma unroll
    for (int m = 0; m < 2; ++m)
#pragma unroll
      for (int i = 0; i < 16; ++i) {
        float v = acc[m][n][i] + b1v;
        v = v > 0.0f ? v : 0.01f * v;
        p[m][i] += v * w2v;
      }
  }
#pragma unroll
  for (int off = 16; off > 0; off >>= 1)
#pragma unroll
    for (int m = 0; m < 2; ++m)
#pragma unroll
      for (int i = 0; i < 16; ++i)
        p[m][i] += __shfl_xor(p[m][i], off, 32);
  if (lr == 0) {
#pragma unroll
    for (int m = 0; m < 2; ++m) {
      int rbase = node_base + r0 + wr * 64 + m * 32 + 4 * hg;
#pragma unroll
      for (int i = 0; i < 16; ++i)
        unsafeAtomicAdd(&z[rbase + (i & 3) + 8 * (i >> 2)], p[m][i]);
    }
  }
}

__device__ void bitonic(unsigned long long* keys, int n, int t, int nt) {
  for (int k = 2; k <= n; k <<= 1)
    for (int jj = k >> 1; jj > 0; jj >>= 1) {
      __syncthreads();
      for (int i = t; i < n; i += nt) {
        int ixj = i ^ jj;
        if (ixj > i) {
          unsigned long long a = keys[i], c = keys[ixj];
          bool up = ((i & k) == 0);
          if ((a > c) == up) { keys[i] = c; keys[ixj] = a; }
        }
      }
    }
  __syncthreads();
}

// FUSED per-graph: score (CSR segment sum, src in bits 15-24) + mask init +
// sentence outputs + both top-k phases. One block per graph, 1024 threads.
__global__ __launch_bounds__(1024) void k_score_topk(
    const unsigned long long* __restrict__ csr, const unsigned* __restrict__ rstart,
    const float* __restrict__ dinv, const float* __restrict__ z,
    const float* __restrict__ b2, int* __restrict__ mask, float* __restrict__ out) {
  __shared__ float sc[1024];
  __shared__ unsigned long long keys[1024];
  int b = blockIdx.x, t = threadIdx.x;
  int base = b << 10;
  int n = base + t;
  mask[n] = -1;
  float dv = dinv[n];
  float a = b2[0] + dv * dv * z[n];
  unsigned s = rstart[n], epos = rstart[n + 1];
  for (unsigned e = s; e < epos; ++e) {
    unsigned long long p = csr[e];
    a += __uint_as_float((unsigned)(p >> 32)) * z[base + (((unsigned)p >> 15) & 1023u)];
  }
  sc[t] = a;
  if (t < 64) {
    out[O6 + b * 64 + t] = a;            // sentence_scores
    out[O7 + b * 64 + t] = (float)b;     // sentence_batch
    keys[t] = ((unsigned long long)(~monof(a)) << 32) | (unsigned)t;
  }
  __syncthreads();
  bitonic(keys, 64, t, 1024);
  if (t < 3) {
    int idx = (int)(keys[t] & 0xFFFFFFFFull);
    int node = base + idx;
    int pos = b * 3 + t;
    mask[node] = pos;
    out[O4 + pos] = (float)node;
    out[O5 + pos] = sc[idx];
    out[O3 + pos] = (float)b;
  }
  __syncthreads();
  keys[t] = (t < 960)
      ? (((unsigned long long)(~monof(sc[64 + t])) << 32) | (unsigned)t)
      : 0xFFFFFFFFFFFFFFFFull;
  __syncthreads();
  bitonic(keys, 1024, t, 1024);
  if (t < 480) {
    int idx = (int)(keys[t] & 0xFFFFFFFFull);
    int node = base + 64 + idx;
    int pos = 192 + b * 480 + t;
    mask[node] = pos;
    out[O4 + pos] = (float)node;
    out[O5 + pos] = sc[64 + idx];
    out[O3 + pos] = (float)b;
  }
}

// Merged tail: blocks 0..2047 = edge outputs; blocks 2048.. = x_out gather
// (4 rows per block, 64 lanes per row).
__global__ __launch_bounds__(256) void k_tail(const int* __restrict__ ei,
    const float* __restrict__ w, const int* __restrict__ mask,
    const float* __restrict__ x, float* __restrict__ out) {
  int bid = blockIdx.x, t = threadIdx.x;
  if (bid < 2048) {
    int e = bid * 256 + t;
    int nr = mask[ei[e]];
    int nc = mask[ei[NE + e]];
    bool keep = (nr >= 0) && (nc >= 0);
    out[O1 + e]      = keep ? (float)nr : -1.0f;
    out[O1 + NE + e] = keep ? (float)nc : -1.0f;
    out[O2 + e]      = keep ? w[e] : 0.0f;
    out[O8 + e]      = keep ? 1.0f : 0.0f;
  } else {
    int i = (bid - 2048) * 4 + (t >> 6);   // row 0..30911
    int lane = t & 63;
    int node = (int)out[O4 + i];
    float s = out[O5 + i];
    float4 v = ((const float4*)&x[node * 256])[lane];
    ((float4*)&out[i * 256])[lane] = make_float4(v.x * s, v.y * s, v.z * s, v.w * s);
  }
}

extern "C" void kernel_launch(void* const* d_in, const int* in_sizes, int n_in,
                              void* d_out, int out_size, void* d_ws, size_t ws_size,
                              hipStream_t stream) {
  (void)in_sizes; (void)n_in; (void)out_size; (void)d_ws; (void)ws_size;
  const float* x  = (const float*)d_in[0];
  const int*   ei = (const int*)d_in[1];
  const float* w  = (const float*)d_in[2];
  const float* W1 = (const float*)d_in[4];
  const float* b1 = (const float*)d_in[5];
  const float* W2 = (const float*)d_in[6];
  const float* b2 = (const float*)d_in[7];
  float* out    = (float*)d_out;
  unsigned short* yhi = (unsigned short*)out;                  // [32768*256] per chunk
  unsigned short* ylo = (unsigned short*)(out + YLO_OFF);
  unsigned long long* csr = (unsigned long long*)(out + CSR_OFF);
  float* dinv   = out + DINV_OFF;
  float* z      = out + Z_OFF;
  unsigned* rstart = (unsigned*)(out + RSTART_OFF);
  unsigned* cursor = (unsigned*)(out + CURSOR_OFF);
  unsigned long long* hist64 = (unsigned long long*)(out + HIST_OFF);
  unsigned short* w1hi = (unsigned short*)(out + W1HI_OFF);
  unsigned short* w1lo = (unsigned short*)(out + W1LO_OFF);
  int*   mask   = (int*)d_out;

  k_zero_w1t<<<288, 256, 0, stream>>>(hist64, z, W1, w1hi, w1lo);
  k_hist<<<2048, 256, 0, stream>>>(ei, w, hist64);
  k_prefix<<<64, 256, 0, stream>>>(hist64, rstart, cursor, dinv);
  k_scatter<<<2048, 256, 0, stream>>>(ei, w, dinv, cursor, csr);
  for (int ch = 0; ch < 2; ++ch) {
    k_aggx<<<512, 1024, 0, stream>>>(x, csr, rstart, dinv, yhi, ylo, ch * 32);
    k_gemm<<<512, 512, 0, stream>>>(yhi, ylo, w1hi, w1lo, b1, W2, z, ch * 32768);
  }
  k_score_topk<<<64, 1024, 0, stream>>>(csr, rstart, dinv, z, b2, mask, out);
  k_tail<<<2048 + 7728, 256, 0, stream>>>(ei, w, mask, x, out);
}

// Round 21
// 220.051 us; speedup vs baseline: 1.0629x; 1.0629x over previous
//
#include <hip/hip_runtime.h>

// Problem constants
#define NN   65536      // N nodes
#define NE   524288     // E edges
#define EPG  8192       // edges per graph

// Output float offsets in d_out (total 10111552 floats)
#define O1 7913472      // ei_new (2*E)
#define O2 8962048      // ea_new (E)
#define O3 9486336      // batch_out (30912)
#define O4 9517248      // perm (30912)
#define O5 9548160      // score_perm (30912)
#define O6 9579072      // sentence_scores (4096)
#define O7 9583168      // sentence_batch (4096)
#define O8 9587264      // keep (E)

// Scratch placement (float offsets), lifetime-verified (same as R9-R19):
#define CSR_OFF    8388608
#define DINV_OFF   9437184
#define Z_OFF      9502720
#define W1HI_OFF   9568256
#define RSTART_OFF 9633792
#define CURSOR_OFF 9699344
#define W1LO_OFF   9764880
#define HIST_OFF   9830416
#define YLO_OFF    4194304   // ushort-plane offsets: yhi at float 0, ylo at float 4194304

typedef __attribute__((ext_vector_type(8))) short bfrag;
typedef __attribute__((ext_vector_type(4))) float f32x4;
typedef __attribute__((ext_vector_type(8))) unsigned short us8;
typedef __attribute__((ext_vector_type(2))) unsigned long long u64x2;

__device__ __forceinline__ unsigned monof(float f) {
  unsigned u = __float_as_uint(f);
  return (u & 0x80000000u) ? ~u : (u | 0x80000000u);  // ascending monotone map
}

__device__ __forceinline__ unsigned short bf16rne(float f) {
  unsigned u = __float_as_uint(f);
  return (unsigned short)((u + 0x7FFFu + ((u >> 16) & 1u)) >> 16);
}

// Merged: zero hist/z (blocks 0..255) + W1 split/transpose (blocks 256..287)
__global__ __launch_bounds__(256) void k_zero_w1t(unsigned long long* __restrict__ hist,
    float* __restrict__ z, const float* __restrict__ W1,
    unsigned short* __restrict__ hi, unsigned short* __restrict__ lo) {
  __shared__ unsigned short sh[64][72], sl[64][72];
  int b = blockIdx.x, t = threadIdx.x;
  if (b < 256) {
    int n = b * 256 + t;
    hist[n] = 0ull;
    z[n] = 0.0f;
    return;
  }
  int bb = b - 256;
  int bk = bb & 3, bc = bb >> 2;
  int k0 = bk * 64, c0 = bc * 64;
#pragma unroll
  for (int s = 0; s < 16; ++s) {
    int i = t + s * 256;
    int k = i >> 6, c = i & 63;
    float v = W1[(k0 + k) * 512 + c0 + c];
    unsigned short h = bf16rne(v);
    float hf = __uint_as_float((unsigned)h << 16);
    sh[c][k] = h;
    sl[c][k] = bf16rne(v - hf);
  }
  __syncthreads();
#pragma unroll
  for (int s = 0; s < 16; ++s) {
    int i = t + s * 256;
    int c = i >> 6, k = i & 63;
    hi[(c0 + c) * 256 + k0 + k] = sh[c][k];
    lo[(c0 + c) * 256 + k0 + k] = sl[c][k];
  }
}

// One packed u64 atomic per edge: count in bits>=40, wsum fixed-point 2^-20 below.
__global__ void k_hist(const int* __restrict__ ei, const float* __restrict__ w,
                       unsigned long long* __restrict__ hist) {
  int e = blockIdx.x * 256 + threadIdx.x;
  if (e < NE) {
    int c = ei[NE + e];
    unsigned long long add = (1ull << 40) |
        (unsigned long long)(unsigned)__float2uint_rn(w[e] * 1048576.0f);
    atomicAdd(&hist[c], add);
  }
}

// Per graph: exclusive prefix over 1024 bins -> rstart/cursor; dinv from fixed-point wsum.
__global__ __launch_bounds__(256) void k_prefix(const unsigned long long* __restrict__ hist,
    unsigned* __restrict__ rstart, unsigned* __restrict__ cursor, float* __restrict__ dinv) {
  __shared__ unsigned tmp[2][256];
  int g = blockIdx.x, t = threadIdx.x;
  int base = g << 10;
  unsigned c[4], sum = 0;
  unsigned long long hv[4];
#pragma unroll
  for (int u = 0; u < 4; ++u) {
    hv[u] = hist[base + t * 4 + u];
    c[u] = (unsigned)(hv[u] >> 40);
    sum += c[u];
  }
  tmp[0][t] = sum;
  __syncthreads();
  int pin = 0;
  for (int off = 1; off < 256; off <<= 1) {
    int pout = pin ^ 1;
    unsigned v = tmp[pin][t];
    if (t >= off) v += tmp[pin][t - off];
    tmp[pout][t] = v;
    __syncthreads();
    pin = pout;
  }
  unsigned run = (t == 0) ? 0u : tmp[pin][t - 1];
#pragma unroll
  for (int u = 0; u < 4; ++u) {
    unsigned pos = (unsigned)(g << 13) + run;   // g*8192 + prefix
    rstart[base + t * 4 + u] = pos;
    cursor[base + t * 4 + u] = pos;
    run += c[u];
  }
#pragma unroll
  for (int u = 0; u < 4; ++u) {
    int n = base + t * 4 + u;
    float wsum = 1.0f + (float)(hv[u] & ((1ull << 40) - 1)) * 9.5367431640625e-07f;
    dinv[n] = rsqrtf(wsum);
  }
  if (g == 0 && t == 0) rstart[NN] = NE;
}

// Scatter edges to dest-sorted CSR:
// entry = coef<<32 | src_local<<15 | src_local*17   (pre-scaled LDS row offset)
__global__ void k_scatter(const int* __restrict__ ei, const float* __restrict__ w,
                          const float* __restrict__ dinv, unsigned* __restrict__ cursor,
                          unsigned long long* __restrict__ csr) {
  int e = blockIdx.x * 256 + threadIdx.x;
  if (e < NE) {
    int r = ei[e], c = ei[NE + e];
    float cf = w[e] * dinv[r] * dinv[c];
    unsigned pos = atomicAdd(&cursor[c], 1u);
    unsigned sl = (unsigned)(r & 1023);
    csr[pos] = ((unsigned long long)__float_as_uint(cf) << 32) |
               (sl << 15) | (sl * 17u);
  }
}

// Aggregate x over normalized adjacency -> y bf16 hi/lo planes.
// (At structural floor: LDS-throughput bound. Whole-graph CSR in LDS,
// stride-17 xs, 8 lanes/edge, 2 cols/lane, sentinel-zero clamp,
// 1024 threads, 140 KB LDS.)
__global__ __launch_bounds__(1024, 1) void k_aggx(const float* __restrict__ x,
    const unsigned long long* __restrict__ csr, const unsigned* __restrict__ rstart,
    const float* __restrict__ dinv, unsigned short* __restrict__ yhi,
    unsigned short* __restrict__ ylo, int gbase) {
  __shared__ float xs[1024 * 17];          // 68 KB, stride-17 rows
  __shared__ unsigned long long es[8193];  // 64 KB CSR + zero sentinel
  __shared__ unsigned rp[1025];            // local segment starts
  __shared__ float dv2[1024];
  int bid = blockIdx.x;
  int g  = bid & 31;                // graph g -> XCD g%8 (L2 locality)
  int cc = bid >> 5;                // 16 chunks of 16 columns
  int gg = gbase + g;
  int c0 = cc * 16;
  int t = threadIdx.x;              // 0..1023
  int nbase = gg << 10;
  unsigned ebase = (unsigned)gg << 13;
  {
    rp[t] = rstart[nbase + t] - ebase;
    float dv = dinv[nbase + t];
    dv2[t] = dv * dv;
  }
  if (t == 0) { rp[1024] = 8192u; es[8192] = 0ull; }
  // stage whole-graph CSR: 4096 x 16B, 4 per thread
  {
    const u64x2* src = (const u64x2*)(csr + ebase);
    u64x2* dst = (u64x2*)es;
#pragma unroll
    for (int i = 0; i < 4; ++i)
      dst[t + i * 1024] = src[t + i * 1024];
  }
  // stage x[:, c0:c0+16]: float4 global loads, scalar LDS writes
#pragma unroll
  for (int s = 0; s < 4; ++s) {
    int i = t + s * 1024;           // float4-slot: row = i>>2, quad = i&3
    int row = i >> 2, q = (i & 3) * 4;
    float4 v = *(const float4*)&x[(nbase + row) * 256 + c0 + q];
    float* d = &xs[row * 17 + q];
    d[0] = v.x; d[1] = v.y; d[2] = v.z; d[3] = v.w;
  }
  __syncthreads();
  int jj = t & 7;                   // 2-col lane: cols c0+2jj, c0+2jj+1
  int h  = (t >> 3) & 1;            // half: segment d0 (h=0) or d1 (h=1)
  int grp = t >> 4;                 // 64 groups of 16 lanes
  int dbase = grp * 16;             // group owns dests [dbase, dbase+16)
  int j2 = 2 * jj;
  for (int dd = 0; dd < 8; ++dd) {
    int d0 = dbase + dd;
    unsigned pA = rp[d0], qA = rp[d0 + 1];
    unsigned pB = rp[d0 + 8], qB = rp[d0 + 9];
    int L0 = (int)(qA - pA), L1 = (int)(qB - pB);
    int L = L0 > L1 ? L0 : L1;      // group-uniform trip count
    int d = d0 + 8 * h;             // this half's dest
    unsigned p = h ? pB : pA;
    unsigned q = h ? qB : qA;
    int dofs = d * 17 + j2;
    float dv = dv2[d];
    float ax = dv * xs[dofs], ay = dv * xs[dofs + 1];
    for (int k = 0; k < L; k += 4) {
      unsigned long long cv[4];
#pragma unroll
      for (int u = 0; u < 4; ++u) {
        unsigned a = p + (unsigned)(k + u);
        cv[u] = es[a < q ? a : 8192u];   // sentinel: coef 0
      }
#pragma unroll
      for (int u = 0; u < 4; ++u) {
        float cf = __uint_as_float((unsigned)(cv[u] >> 32));
        unsigned o = ((unsigned)cv[u] & 0x7FFFu) + (unsigned)j2;
        ax += cf * xs[o];
        ay += cf * xs[o + 1];
      }
    }
    int idx = ((g << 10) + d) * 256 + c0 + j2;
    unsigned short hx = bf16rne(ax), hy = bf16rne(ay);
    float lx = ax - __uint_as_float((unsigned)hx << 16);
    float ly = ay - __uint_as_float((unsigned)hy << 16);
    *(unsigned*)&yhi[idx] = (unsigned)hx | ((unsigned)hy << 16);
    *(unsigned*)&ylo[idx] = (unsigned)bf16rne(lx) | ((unsigned)bf16rne(ly) << 16);
  }
}

// MFMA GEMM (R19 proven): 512 threads, 128x256 tile, DOUBLE-BUFFERED LDS (one
// barrier per k-step). Prefetch registers carry next step's data across the
// MFMA section; writes go to the alternate buffer. 16x16x32 bf16, hi/lo
// 3-product split, fused +b1 -> LeakyReLU -> dot W2 -> atomic z.
__global__ __launch_bounds__(512, 2) void k_gemm(
    const unsigned short* __restrict__ yhi, const unsigned short* __restrict__ ylo,
    const unsigned short* __restrict__ w1hi, const unsigned short* __restrict__ w1lo,
    const float* __restrict__ b1, const float* __restrict__ W2,
    float* __restrict__ z, int node_base) {
  __shared__ unsigned short Ah_s[2][128 * 40], Al_s[2][128 * 40];  // 10.2 KB each buf
  __shared__ unsigned short Bh_s[2][256 * 40], Bl_s[2][256 * 40];  // 20.5 KB each buf
  int bx = blockIdx.x & 1, by = blockIdx.x >> 1;
  int r0 = by * 128, c0 = bx * 256;
  int t = threadIdx.x;
  int lane = t & 63, wid = t >> 6;           // 8 waves
  int wr = wid >> 2, wc = wid & 3;           // wave tile origin (wr*64, wc*64)
  int lr = lane & 15, hg = lane >> 4;
  f32x4 acc[4][4];
#pragma unroll
  for (int m = 0; m < 4; ++m)
#pragma unroll
    for (int n = 0; n < 4; ++n)
      acc[m][n] = (f32x4){0.0f, 0.0f, 0.0f, 0.0f};
  // staging coords: A rows (1 us8/plane), B cols (2 us8/plane)
  int ar = t >> 2, ak = (t & 3) * 8;         // A: row 0..127, k-chunk
  int bc = t >> 1, bk = (t & 1) * 16;        // B: col 0..255, k-chunks bk, bk+8
  const unsigned short* pya = &yhi [(r0 + ar) * 256 + ak];
  const unsigned short* pyb = &ylo [(r0 + ar) * 256 + ak];
  const unsigned short* pw0 = &w1hi[(c0 + bc) * 256 + bk];
  const unsigned short* pw1 = &w1lo[(c0 + bc) * 256 + bk];
  us8 va, vb, vc0, vc1, vd0, vd1;
  // prologue: stage k-step 0 into buf 0
  va  = *(const us8*)&pya[0];
  vb  = *(const us8*)&pyb[0];
  vc0 = *(const us8*)&pw0[0];
  vc1 = *(const us8*)&pw0[8];
  vd0 = *(const us8*)&pw1[0];
  vd1 = *(const us8*)&pw1[8];
  *(us8*)&Ah_s[0][ar * 40 + ak] = va;
  *(us8*)&Al_s[0][ar * 40 + ak] = vb;
  *(us8*)&Bh_s[0][bc * 40 + bk] = vc0;
  *(us8*)&Bh_s[0][bc * 40 + bk + 8] = vc1;
  *(us8*)&Bl_s[0][bc * 40 + bk] = vd0;
  *(us8*)&Bl_s[0][bc * 40 + bk + 8] = vd1;
  __syncthreads();
#pragma unroll
  for (int s = 0; s < 8; ++s) {
    int cur = s & 1, nxt = cur ^ 1;
    int kn = (s < 7) ? (s + 1) * 32 : s * 32;  // clamped prefetch (branch-free)
    va  = *(const us8*)&pya[kn];
    vb  = *(const us8*)&pyb[kn];
    vc0 = *(const us8*)&pw0[kn];
    vc1 = *(const us8*)&pw0[kn + 8];
    vd0 = *(const us8*)&pw1[kn];
    vd1 = *(const us8*)&pw1[kn + 8];
    bfrag Ah[4], Al[4], Bh[4], Bl[4];
#pragma unroll
    for (int m = 0; m < 4; ++m) {
      int ra = (wr * 64 + m * 16 + lr) * 40 + hg * 8;
      Ah[m] = *(const bfrag*)&Ah_s[cur][ra];
      Al[m] = *(const bfrag*)&Al_s[cur][ra];
      int rb = (wc * 64 + m * 16 + lr) * 40 + hg * 8;
      Bh[m] = *(const bfrag*)&Bh_s[cur][rb];
      Bl[m] = *(const bfrag*)&Bl_s[cur][rb];
    }
#pragma unroll
    for (int m = 0; m < 4; ++m)
#pragma unroll
      for (int n = 0; n < 4; ++n) {
        acc[m][n] = __builtin_amdgcn_mfma_f32_16x16x32_bf16(Ah[m], Bh[n], acc[m][n], 0, 0, 0);
        acc[m][n] = __builtin_amdgcn_mfma_f32_16x16x32_bf16(Ah[m], Bl[n], acc[m][n], 0, 0, 0);
        acc[m][n] = __builtin_amdgcn_mfma_f32_16x16x32_bf16(Al[m], Bh[n], acc[m][n], 0, 0, 0);
      }
    // write next step's data to the alternate buffer, then the single barrier
    *(us8*)&Ah_s[nxt][ar * 40 + ak] = va;
    *(us8*)&Al_s[nxt][ar * 40 + ak] = vb;
    *(us8*)&Bh_s[nxt][bc * 40 + bk] = vc0;
    *(us8*)&Bh_s[nxt][bc * 40 + bk + 8] = vc1;
    *(us8*)&Bl_s[nxt][bc * 40 + bk] = vd0;
    *(us8*)&Bl_s[nxt][bc * 40 + bk + 8] = vd1;
    __syncthreads();
  }
  // epilogue: +b1, LeakyReLU, dot W2, reduce over the 16 col-lanes, atomic z
  float p[4][4];
#pragma unroll
  for (int m = 0; m < 4; ++m)
#pragma unroll
    for (int i = 0; i < 4; ++i) p[m][i] = 0.0f;
#pragma unroll
  for (int n = 0; n < 4; ++n) {
    int col = c0 + wc * 64 + n * 16 + lr;
    float b1v = b1[col], w2v = W2[col];
#pragma unroll
    for (int m = 0; m < 4; ++m)
#pragma unroll
      for (int i = 0; i < 4; ++i) {
        float v = acc[m][n][i] + b1v;
        v = v > 0.0f ? v : 0.01f * v;
        p[m][i] += v * w2v;
      }
  }
#pragma unroll
  for (int off = 8; off > 0; off >>= 1)
#pragma unroll
    for (int m = 0; m < 4; ++m)
#pragma unroll
      for (int i = 0; i < 4; ++i)
        p[m][i] += __shfl_xor(p[m][i], off, 16);
  if (lr == 0) {
    int rbase = node_base + r0 + wr * 64 + hg * 4;
#pragma unroll
    for (int m = 0; m < 4; ++m)
#pragma unroll
      for (int i = 0; i < 4; ++i)
        unsafeAtomicAdd(&z[rbase + m * 16 + i], p[m][i]);
  }
}

__device__ void bitonic(unsigned long long* keys, int n, int t, int nt) {
  for (int k = 2; k <= n; k <<= 1)
    for (int jj = k >> 1; jj > 0; jj >>= 1) {
      __syncthreads();
      for (int i = t; i < n; i += nt) {
        int ixj = i ^ jj;
        if (ixj > i) {
          unsigned long long a = keys[i], c = keys[ixj];
          bool up = ((i & k) == 0);
          if ((a > c) == up) { keys[i] = c; keys[ixj] = a; }
        }
      }
    }
  __syncthreads();
}

// FUSED per-graph: score (CSR segment sum, src in bits 15-24) + mask init +
// sentence outputs + both top-k phases. One block per graph, 1024 threads.
__global__ __launch_bounds__(1024) void k_score_topk(
    const unsigned long long* __restrict__ csr, const unsigned* __restrict__ rstart,
    const float* __restrict__ dinv, const float* __restrict__ z,
    const float* __restrict__ b2, int* __restrict__ mask, float* __restrict__ out) {
  __shared__ float sc[1024];
  __shared__ unsigned long long keys[1024];
  int b = blockIdx.x, t = threadIdx.x;
  int base = b << 10;
  int n = base + t;
  mask[n] = -1;
  float dv = dinv[n];
  float a = b2[0] + dv * dv * z[n];
  unsigned s = rstart[n], epos = rstart[n + 1];
  for (unsigned e = s; e < epos; ++e) {
    unsigned long long p = csr[e];
    a += __uint_as_float((unsigned)(p >> 32)) * z[base + (((unsigned)p >> 15) & 1023u)];
  }
  sc[t] = a;
  if (t < 64) {
    out[O6 + b * 64 + t] = a;            // sentence_scores
    out[O7 + b * 64 + t] = (float)b;     // sentence_batch
    keys[t] = ((unsigned long long)(~monof(a)) << 32) | (unsigned)t;
  }
  __syncthreads();
  bitonic(keys, 64, t, 1024);
  if (t < 3) {
    int idx = (int)(keys[t] & 0xFFFFFFFFull);
    int node = base + idx;
    int pos = b * 3 + t;
    mask[node] = pos;
    out[O4 + pos] = (float)node;
    out[O5 + pos] = sc[idx];
    out[O3 + pos] = (float)b;
  }
  __syncthreads();
  keys[t] = (t < 960)
      ? (((unsigned long long)(~monof(sc[64 + t])) << 32) | (unsigned)t)
      : 0xFFFFFFFFFFFFFFFFull;
  __syncthreads();
  bitonic(keys, 1024, t, 1024);
  if (t < 480) {
    int idx = (int)(keys[t] & 0xFFFFFFFFull);
    int node = base + 64 + idx;
    int pos = 192 + b * 480 + t;
    mask[node] = pos;
    out[O4 + pos] = (float)node;
    out[O5 + pos] = sc[64 + idx];
    out[O3 + pos] = (float)b;
  }
}

// Merged tail: blocks 0..2047 = edge outputs; blocks 2048.. = x_out gather
// (4 rows per block, 64 lanes per row).
__global__ __launch_bounds__(256) void k_tail(const int* __restrict__ ei,
    const float* __restrict__ w, const int* __restrict__ mask,
    const float* __restrict__ x, float* __restrict__ out) {
  int bid = blockIdx.x, t = threadIdx.x;
  if (bid < 2048) {
    int e = bid * 256 + t;
    int nr = mask[ei[e]];
    int nc = mask[ei[NE + e]];
    bool keep = (nr >= 0) && (nc >= 0);
    out[O1 + e]      = keep ? (float)nr : -1.0f;
    out[O1 + NE + e] = keep ? (float)nc : -1.0f;
    out[O2 + e]      = keep ? w[e] : 0.0f;
    out[O8 + e]      = keep ? 1.0f : 0.0f;
  } else {
    int i = (bid - 2048) * 4 + (t >> 6);   // row 0..30911
    int lane = t & 63;
    int node = (int)out[O4 + i];
    float s = out[O5 + i];
    float4 v = ((const float4*)&x[node * 256])[lane];
    ((float4*)&out[i * 256])[lane] = make_float4(v.x * s, v.y * s, v.z * s, v.w * s);
  }
}

extern "C" void kernel_launch(void* const* d_in, const int* in_sizes, int n_in,
                              void* d_out, int out_size, void* d_ws, size_t ws_size,
                              hipStream_t stream) {
  (void)in_sizes; (void)n_in; (void)out_size; (void)d_ws; (void)ws_size;
  const float* x  = (const float*)d_in[0];
  const int*   ei = (const int*)d_in[1];
  const float* w  = (const float*)d_in[2];
  const float* W1 = (const float*)d_in[4];
  const float* b1 = (const float*)d_in[5];
  const float* W2 = (const float*)d_in[6];
  const float* b2 = (const float*)d_in[7];
  float* out    = (float*)d_out;
  unsigned short* yhi = (unsigned short*)out;                  // [32768*256] per chunk
  unsigned short* ylo = (unsigned short*)(out + YLO_OFF);
  unsigned long long* csr = (unsigned long long*)(out + CSR_OFF);
  float* dinv   = out + DINV_OFF;
  float* z      = out + Z_OFF;
  unsigned* rstart = (unsigned*)(out + RSTART_OFF);
  unsigned* cursor = (unsigned*)(out + CURSOR_OFF);
  unsigned long long* hist64 = (unsigned long long*)(out + HIST_OFF);
  unsigned short* w1hi = (unsigned short*)(out + W1HI_OFF);
  unsigned short* w1lo = (unsigned short*)(out + W1LO_OFF);
  int*   mask   = (int*)d_out;

  k_zero_w1t<<<288, 256, 0, stream>>>(hist64, z, W1, w1hi, w1lo);
  k_hist<<<2048, 256, 0, stream>>>(ei, w, hist64);
  k_prefix<<<64, 256, 0, stream>>>(hist64, rstart, cursor, dinv);
  k_scatter<<<2048, 256, 0, stream>>>(ei, w, dinv, cursor, csr);
  for (int ch = 0; ch < 2; ++ch) {
    k_aggx<<<512, 1024, 0, stream>>>(x, csr, rstart, dinv, yhi, ylo, ch * 32);
    k_gemm<<<512, 512, 0, stream>>>(yhi, ylo, w1hi, w1lo, b1, W2, z, ch * 32768);
  }
  k_score_topk<<<64, 1024, 0, stream>>>(csr, rstart, dinv, z, b2, mask, out);
  k_tail<<<2048 + 7728, 256, 0, stream>>>(ei, w, mask, x, out);
}